// Round 6
// baseline (418.151 us; speedup 1.0000x reference)
//
#include <hip/hip_runtime.h>
#include <cstdint>
#include <cstddef>

// SSM layer: y = scan(x @ B^T) @ C^T + D * x
// x: (8,4096,1024) f32; A: (256,); B: (256,1024); C: (1024,256); D: (1024,)
// M = 32768 rows. Pipeline (R6):
//   cvt (B,C -> f16) -> gemm_bx(+fused scan_E) -> scan_prefix -> gemm_y_scan
// R6 = R5 with the gemm_y_scan staging-loop bug fixed: p<16 -> p<8.
//   (R5 wrote 32KB past the 32KB LDS tile: r = p*8+(tid>>5) reached 127 on a
//   64-row buffer -> LDS OOB write -> GPU fault -> "container failed twice".)
// R5 design: scan_apply FUSED into gemm_y (block = one 64-row chunk):
//   stage pre-scan Bx tile -> LDS, run the 64-step scan in-LDS (identical
//   numerics to scan_apply: f32 accum, f16 writeback), read af frags from
//   LDS, then BARRIER-FREE column streaming with C fragments read directly
//   from L2-resident Ch (512KB; no LDS slab, no main-loop syncthreads).
//   Kills: scan_apply launch + 34MB HBM round-trip + gemm_y's 8 barrier
//   pairs. Cost: 4x wave-redundant C reads (~1GB L2-local) hidden under the
//   HBM floor.

typedef __attribute__((ext_vector_type(8))) _Float16 half8;
typedef __attribute__((ext_vector_type(4))) float f32x4;

__device__ inline half8 cvt8(float4 a, float4 b) {
  half8 h;
  h[0] = (_Float16)a.x; h[1] = (_Float16)a.y;
  h[2] = (_Float16)a.z; h[3] = (_Float16)a.w;
  h[4] = (_Float16)b.x; h[5] = (_Float16)b.y;
  h[6] = (_Float16)b.z; h[7] = (_Float16)b.w;
  return h;
}

// ---------------------------------------------------------------------------
// Convert B (256x1024) and C (1024x256) to f16. 65536 threads x 8 elems.
// ---------------------------------------------------------------------------
__global__ __launch_bounds__(256) void cvt_bc(
    const float* __restrict__ Bp, const float* __restrict__ Cp,
    _Float16* __restrict__ Bh, _Float16* __restrict__ Ch)
{
  const int g = blockIdx.x * 256 + threadIdx.x;      // 0..65535
  const size_t off = (size_t)(g & 32767) * 8;
  const float* src = (g < 32768) ? (Bp + off) : (Cp + off);
  _Float16*    dst = (g < 32768) ? (Bh + off) : (Ch + off);
  float4 a = *(const float4*)src;
  float4 b = *(const float4*)(src + 4);
  *(half8*)dst = cvt8(a, b);
}

// ---------------------------------------------------------------------------
// GEMM1: Bx[M,256] = x[M,1024] * B[256,1024]^T  (f16 out) + fused scan_E.
// Block = 64 rows (= one scan chunk); wave w owns rows w*16..+15 x ALL 256 n.
// B-slab chunk (256n x 128k f16 = 64KB, XOR-swizzled) in LDS, refilled from
// L2 each K-chunk. A-fragments stream straight from global x.
// Epilogue bounces the 64x256 f16 tile through LDS for coalesced stores AND
// computes E[chunk][n] = 64-step scan sum from the same LDS tile.
// ---------------------------------------------------------------------------
__global__ __launch_bounds__(256) void gemm_bx(
    const float* __restrict__ x, const _Float16* __restrict__ Bh,
    const float* __restrict__ Ap,
    _Float16* __restrict__ Bxh, float* __restrict__ E)
{
  __shared__ _Float16 lb[256 * 128];   // 64KB, [n][k8p*8], k8p = k8 ^ (n&7)

  const int tid  = threadIdx.x;
  const int lane = tid & 63;
  const int wave = tid >> 6;
  const int quad = lane >> 4;
  const int l16  = lane & 15;
  const long blockM = (long)blockIdx.x * 64;
  const long arow = blockM + wave * 16 + l16;     // global A row for frags

  f32x4 acc[16];
  #pragma unroll
  for (int i = 0; i < 16; i++) acc[i] = (f32x4){0.f, 0.f, 0.f, 0.f};

  for (int kc = 0; kc < 8; kc++) {
    __syncthreads();   // previous chunk's readers done
    // fill B-slab: thread t = row n, 16 x 16B from L2-resident Bh
    {
      const int n = tid;
      const _Float16* src = Bh + (size_t)n * 1024 + kc * 128;
      #pragma unroll
      for (int j = 0; j < 16; j++) {
        half8 v = *(const half8*)(src + j * 8);
        const int k8p = j ^ (n & 7);
        *(half8*)&lb[n * 128 + k8p * 8] = v;
      }
    }
    // A-fragments for this chunk (4 ks), direct from x
    half8 af[4];
    #pragma unroll
    for (int ks = 0; ks < 4; ks++) {
      const float* ga = x + arow * 1024 + kc * 128 + ks * 32 + quad * 8;
      float4 a0 = *(const float4*)ga;
      float4 a1 = *(const float4*)(ga + 4);
      af[ks] = cvt8(a0, a1);
    }
    __syncthreads();
    #pragma unroll
    for (int ks = 0; ks < 4; ks++) {
      #pragma unroll
      for (int nt = 0; nt < 16; nt++) {
        const int n   = nt * 16 + l16;
        const int k8p = (ks * 4 + quad) ^ (n & 7);
        half8 bf = *(const half8*)&lb[n * 128 + k8p * 8];
        acc[nt] = __builtin_amdgcn_mfma_f32_16x16x32_f16(af[ks], bf, acc[nt], 0, 0, 0);
      }
    }
  }

  // epilogue: bounce through LDS -> coalesced f16 stores + fused scan_E.
  __syncthreads();
  #pragma unroll
  for (int nt = 0; nt < 16; nt++)
    #pragma unroll
    for (int r = 0; r < 4; r++)
      lb[(wave * 16 + quad * 4 + r) * 256 + nt * 16 + l16] = (_Float16)acc[nt][r];
  __syncthreads();
  {
    const int row = tid >> 2, seg = tid & 3;       // 64 rows x 4 segs
    _Float16* dst = Bxh + (blockM + row) * 256 + seg * 64;
    const _Float16* srcl = &lb[row * 256 + seg * 64];
    #pragma unroll
    for (int j = 0; j < 8; j++)
      *(half8*)(dst + j * 8) = *(const half8*)(srcl + j * 8);
  }
  {
    // fused scan_E: thread tid = state index n; 64-step serial scan over the
    // LDS tile (same f16 values that were just stored -> bit-identical).
    const float al = expf(-expf(Ap[tid]));
    float h = 0.f;
    #pragma unroll 8
    for (int t = 0; t < 64; t++)
      h = fmaf(al, h, (float)lb[t * 256 + tid]);
    E[(size_t)blockIdx.x * 256 + tid] = h;
  }
}

// ---------------------------------------------------------------------------
// scan_prefix: per batch b, serial prefix over 64 chunk sums.
// Bulk-load the 64x256 f32 E-slice (64KB) into LDS with pipelined float4
// loads, then run the serial recurrence out of LDS.
// ---------------------------------------------------------------------------
__global__ __launch_bounds__(256) void scan_prefix(
    const float* __restrict__ E, const float* __restrict__ Ap,
    float* __restrict__ carry)
{
  __shared__ float4 se4[4096];                     // 64KB = 64 chunks x 256 n
  const int n = threadIdx.x;
  const int b = blockIdx.x;

  const float4* src4 = (const float4*)(E + (size_t)b * 64 * 256);
  #pragma unroll
  for (int j = 0; j < 16; j++)
    se4[j * 256 + n] = src4[j * 256 + n];

  const float al = expf(-expf(Ap[n]));
  float aL = al;
  #pragma unroll
  for (int i = 0; i < 6; i++) aL *= aL;            // al^64

  __syncthreads();
  const float* se = (const float*)se4;
  float run = 0.f;
  for (int c = 0; c < 64; c++) {
    carry[((size_t)b * 64 + c) * 256 + n] = run;
    run = fmaf(aL, run, se[c * 256 + n]);
  }
}

// ---------------------------------------------------------------------------
// GEMM2 (+fused scan_apply): y[chunk rows, :] = scan(Bx_chunk) @ C^T + D*x
// Block = one 64-row chunk x one 512-col half (grid = 512*2).
//   1. stage pre-scan Bx tile (64x256 f16 = 32KB) -> LDS, XOR-swizzled,
//      flat coalesced loads. 8 iterations x 256 threads x 8 halfs = 16384.
//   2. in-LDS scan: thread = state n, h = carry[chunk][n]; 64 serial
//      f32 fmaf steps, f16 writeback (identical numerics to old scan_apply).
//   3. af fragments (wave's 16 rows x 256 k) from LDS -> registers.
//   4. barrier-free column streaming: 8 slabs x 64 cols; C fragments read
//      DIRECTLY from L2-resident Ch (16B scattered loads); swapped-operand
//      MFMA -> lane owns 4 consecutive y cols -> float4 x/D loads, y stores.
// ---------------------------------------------------------------------------
__global__ __launch_bounds__(256, 4) void gemm_y_scan(
    const _Float16* __restrict__ Bxh, const _Float16* __restrict__ Ch,
    const float* __restrict__ x, const float* __restrict__ Dp,
    const float* __restrict__ Ap, const float* __restrict__ carry,
    float* __restrict__ y)
{
  __shared__ _Float16 lb[64 * 256];   // 32KB, [t][k8p*8+e], k8p = k8 ^ (t&7)

  const int tid  = threadIdx.x;
  const int lane = tid & 63;
  const int wave = tid >> 6;          // 0..3
  const int quad = lane >> 4;
  const int l16  = lane & 15;
  const int cg   = blockIdx.x & 1;    // column half: cols cg*512 .. +511
  const long mg  = blockIdx.x >> 1;   // chunk 0..511

  // 1. stage pre-scan Bx tile, flat coalesced half8 loads, XOR swizzle dest.
  //    64x256 f16 = 16384 elems = 8 iters x 256 thr x 8 halfs (r in 0..63).
  {
    const _Float16* src = Bxh + mg * 64 * 256;
    #pragma unroll
    for (int p = 0; p < 8; p++) {
      half8 v = *(const half8*)(src + p * 2048 + tid * 8);
      const int r   = p * 8 + (tid >> 5);          // tile row (time step)
      const int k8p = (tid & 31) ^ (r & 7);
      *(half8*)&lb[r * 256 + k8p * 8] = v;
    }
  }
  __syncthreads();

  // 2. in-LDS scan: thread owns state n = tid. Same math as old scan_apply.
  {
    const float al = expf(-expf(Ap[tid]));
    float h = carry[mg * 256 + tid];
    const int k8 = tid >> 3, e = tid & 7;
    #pragma unroll 8
    for (int t = 0; t < 64; t++) {
      const int idx = t * 256 + ((k8 ^ (t & 7)) * 8 + e);
      h = fmaf(al, h, (float)lb[idx]);
      lb[idx] = (_Float16)h;
    }
  }
  __syncthreads();

  // 3. af fragments from LDS: wave's 16 rows x 256 k (8 x ds_read_b128).
  const long row = mg * 64 + wave * 16 + l16;     // this lane's y row
  half8 af[8];
  {
    const int r = wave * 16 + l16;
    #pragma unroll
    for (int ks = 0; ks < 8; ks++) {
      const int k8p = (ks * 4 + quad) ^ (r & 7);
      af[ks] = *(const half8*)&lb[r * 256 + k8p * 8];
    }
  }

  // 4. barrier-free column streaming; C fragments direct from L2.
  const float* px = x + row * 1024;
  float*       py = y + row * 1024;
  for (int it = 0; it < 8; it++) {
    const int n0 = cg * 512 + it * 64;

    float4 xv[4], dv[4];
    #pragma unroll
    for (int nt = 0; nt < 4; nt++) {
      xv[nt] = *(const float4*)(px + n0 + nt * 16 + quad * 4);
      dv[nt] = *(const float4*)(Dp + n0 + nt * 16 + quad * 4);
    }

    f32x4 acc[4];
    #pragma unroll
    for (int nt = 0; nt < 4; nt++) acc[nt] = (f32x4){0.f, 0.f, 0.f, 0.f};

    #pragma unroll
    for (int ks = 0; ks < 8; ks++) {
      #pragma unroll
      for (int nt = 0; nt < 4; nt++) {
        const half8 cf = *(const half8*)(
            Ch + (size_t)(n0 + nt * 16 + l16) * 256 + ks * 32 + quad * 8);
        acc[nt] = __builtin_amdgcn_mfma_f32_16x16x32_f16(cf, af[ks], acc[nt], 0, 0, 0);
      }
    }

    // epilogue: y = acc + D*x, 4 consecutive cols per lane (float4 stores)
    #pragma unroll
    for (int nt = 0; nt < 4; nt++) {
      float4 o;
      o.x = acc[nt][0] + dv[nt].x * xv[nt].x;
      o.y = acc[nt][1] + dv[nt].y * xv[nt].y;
      o.z = acc[nt][2] + dv[nt].z * xv[nt].z;
      o.w = acc[nt][3] + dv[nt].w * xv[nt].w;
      *(float4*)(py + n0 + nt * 16 + quad * 4) = o;
    }
  }
}

// ---------------------------------------------------------------------------
extern "C" void kernel_launch(void* const* d_in, const int* in_sizes, int n_in,
                              void* d_out, int out_size, void* d_ws, size_t ws_size,
                              hipStream_t stream) {
  const float* x  = (const float*)d_in[0];
  const float* Ap = (const float*)d_in[1];
  const float* Bp = (const float*)d_in[2];
  const float* Cp = (const float*)d_in[3];
  const float* Dp = (const float*)d_in[4];
  float* y = (float*)d_out;

  // ws: Bxh 16.8MB | Bh 512KB | Ch 512KB | E 512KB | carry 512KB
  _Float16* Bxh = (_Float16*)d_ws;
  _Float16* Bh  = Bxh + (size_t)32768 * 256;
  _Float16* Ch  = Bh + (size_t)256 * 1024;
  float* E      = (float*)(Ch + (size_t)1024 * 256);
  float* carry  = E + (size_t)512 * 256;

  cvt_bc     <<<256,  256, 0, stream>>>(Bp, Cp, Bh, Ch);
  gemm_bx    <<<512,  256, 0, stream>>>(x, Bh, Ap, Bxh, E);
  scan_prefix<<<8,    256, 0, stream>>>(E, Ap, carry);
  gemm_y_scan<<<1024, 256, 0, stream>>>(Bxh, Ch, x, Dp, Ap, carry, y);
}

// Round 7
// 320.929 us; speedup vs baseline: 1.3029x; 1.3029x over previous
//
#include <hip/hip_runtime.h>
#include <cstdint>
#include <cstddef>

// SSM layer: y = scan(x @ B^T) @ C^T + D * x
// x: (8,4096,1024) f32; A: (256,); B: (256,1024); C: (1024,256); D: (1024,)
// M = 32768 rows. Pipeline (R7):
//   cvt (B,C -> f16) -> gemm_bx(+fused scan_E) -> scan_prefix -> gemm_y_scan
// R7: keep R6's scan fusion, REINSTATE R4's LDS C-slab (pre-committed
//   fallback). R6's 160us regression isolated to direct-from-L2 C fragment
//   loads: 64 lanes scatter across 16x 512B-strided rows per instruction
//   (16 separate 64B segments), 256 loads/lane, 4x wave-redundant, VGPR=44
//   -> serialized, latency-bound (hbm 1.46 TB/s, MfmaUtil 4.2).
//   Fix: after af-fragment extraction the 32KB Bx tile in LDS is dead ->
//   REUSE it as the C-slab; phase 4 = R4's verified slab loop (coalesced
//   fill from L2-resident Ch, swizzled ds_read_b128, 2 barriers/slab).
//   LDS stays 32KB -> 4 blocks/CU.

typedef __attribute__((ext_vector_type(8))) _Float16 half8;
typedef __attribute__((ext_vector_type(4))) float f32x4;

__device__ inline half8 cvt8(float4 a, float4 b) {
  half8 h;
  h[0] = (_Float16)a.x; h[1] = (_Float16)a.y;
  h[2] = (_Float16)a.z; h[3] = (_Float16)a.w;
  h[4] = (_Float16)b.x; h[5] = (_Float16)b.y;
  h[6] = (_Float16)b.z; h[7] = (_Float16)b.w;
  return h;
}

// ---------------------------------------------------------------------------
// Convert B (256x1024) and C (1024x256) to f16. 65536 threads x 8 elems.
// ---------------------------------------------------------------------------
__global__ __launch_bounds__(256) void cvt_bc(
    const float* __restrict__ Bp, const float* __restrict__ Cp,
    _Float16* __restrict__ Bh, _Float16* __restrict__ Ch)
{
  const int g = blockIdx.x * 256 + threadIdx.x;      // 0..65535
  const size_t off = (size_t)(g & 32767) * 8;
  const float* src = (g < 32768) ? (Bp + off) : (Cp + off);
  _Float16*    dst = (g < 32768) ? (Bh + off) : (Ch + off);
  float4 a = *(const float4*)src;
  float4 b = *(const float4*)(src + 4);
  *(half8*)dst = cvt8(a, b);
}

// ---------------------------------------------------------------------------
// GEMM1: Bx[M,256] = x[M,1024] * B[256,1024]^T  (f16 out) + fused scan_E.
// Block = 64 rows (= one scan chunk); wave w owns rows w*16..+15 x ALL 256 n.
// B-slab chunk (256n x 128k f16 = 64KB, XOR-swizzled) in LDS, refilled from
// L2 each K-chunk. A-fragments stream straight from global x.
// Epilogue bounces the 64x256 f16 tile through LDS for coalesced stores AND
// computes E[chunk][n] = 64-step scan sum from the same LDS tile.
// ---------------------------------------------------------------------------
__global__ __launch_bounds__(256) void gemm_bx(
    const float* __restrict__ x, const _Float16* __restrict__ Bh,
    const float* __restrict__ Ap,
    _Float16* __restrict__ Bxh, float* __restrict__ E)
{
  __shared__ _Float16 lb[256 * 128];   // 64KB, [n][k8p*8], k8p = k8 ^ (n&7)

  const int tid  = threadIdx.x;
  const int lane = tid & 63;
  const int wave = tid >> 6;
  const int quad = lane >> 4;
  const int l16  = lane & 15;
  const long blockM = (long)blockIdx.x * 64;
  const long arow = blockM + wave * 16 + l16;     // global A row for frags

  f32x4 acc[16];
  #pragma unroll
  for (int i = 0; i < 16; i++) acc[i] = (f32x4){0.f, 0.f, 0.f, 0.f};

  for (int kc = 0; kc < 8; kc++) {
    __syncthreads();   // previous chunk's readers done
    // fill B-slab: thread t = row n, 16 x 16B from L2-resident Bh
    {
      const int n = tid;
      const _Float16* src = Bh + (size_t)n * 1024 + kc * 128;
      #pragma unroll
      for (int j = 0; j < 16; j++) {
        half8 v = *(const half8*)(src + j * 8);
        const int k8p = j ^ (n & 7);
        *(half8*)&lb[n * 128 + k8p * 8] = v;
      }
    }
    // A-fragments for this chunk (4 ks), direct from x
    half8 af[4];
    #pragma unroll
    for (int ks = 0; ks < 4; ks++) {
      const float* ga = x + arow * 1024 + kc * 128 + ks * 32 + quad * 8;
      float4 a0 = *(const float4*)ga;
      float4 a1 = *(const float4*)(ga + 4);
      af[ks] = cvt8(a0, a1);
    }
    __syncthreads();
    #pragma unroll
    for (int ks = 0; ks < 4; ks++) {
      #pragma unroll
      for (int nt = 0; nt < 16; nt++) {
        const int n   = nt * 16 + l16;
        const int k8p = (ks * 4 + quad) ^ (n & 7);
        half8 bf = *(const half8*)&lb[n * 128 + k8p * 8];
        acc[nt] = __builtin_amdgcn_mfma_f32_16x16x32_f16(af[ks], bf, acc[nt], 0, 0, 0);
      }
    }
  }

  // epilogue: bounce through LDS -> coalesced f16 stores + fused scan_E.
  __syncthreads();
  #pragma unroll
  for (int nt = 0; nt < 16; nt++)
    #pragma unroll
    for (int r = 0; r < 4; r++)
      lb[(wave * 16 + quad * 4 + r) * 256 + nt * 16 + l16] = (_Float16)acc[nt][r];
  __syncthreads();
  {
    const int row = tid >> 2, seg = tid & 3;       // 64 rows x 4 segs
    _Float16* dst = Bxh + (blockM + row) * 256 + seg * 64;
    const _Float16* srcl = &lb[row * 256 + seg * 64];
    #pragma unroll
    for (int j = 0; j < 8; j++)
      *(half8*)(dst + j * 8) = *(const half8*)(srcl + j * 8);
  }
  {
    // fused scan_E: thread tid = state index n; 64-step serial scan over the
    // LDS tile (same f16 values that were just stored -> bit-identical).
    const float al = expf(-expf(Ap[tid]));
    float h = 0.f;
    #pragma unroll 8
    for (int t = 0; t < 64; t++)
      h = fmaf(al, h, (float)lb[t * 256 + tid]);
    E[(size_t)blockIdx.x * 256 + tid] = h;
  }
}

// ---------------------------------------------------------------------------
// scan_prefix: per batch b, serial prefix over 64 chunk sums.
// Bulk-load the 64x256 f32 E-slice (64KB) into LDS with pipelined float4
// loads, then run the serial recurrence out of LDS.
// ---------------------------------------------------------------------------
__global__ __launch_bounds__(256) void scan_prefix(
    const float* __restrict__ E, const float* __restrict__ Ap,
    float* __restrict__ carry)
{
  __shared__ float4 se4[4096];                     // 64KB = 64 chunks x 256 n
  const int n = threadIdx.x;
  const int b = blockIdx.x;

  const float4* src4 = (const float4*)(E + (size_t)b * 64 * 256);
  #pragma unroll
  for (int j = 0; j < 16; j++)
    se4[j * 256 + n] = src4[j * 256 + n];

  const float al = expf(-expf(Ap[n]));
  float aL = al;
  #pragma unroll
  for (int i = 0; i < 6; i++) aL *= aL;            // al^64

  __syncthreads();
  const float* se = (const float*)se4;
  float run = 0.f;
  for (int c = 0; c < 64; c++) {
    carry[((size_t)b * 64 + c) * 256 + n] = run;
    run = fmaf(aL, run, se[c * 256 + n]);
  }
}

// ---------------------------------------------------------------------------
// GEMM2 (+fused scan_apply): y[chunk rows, :] = scan(Bx_chunk) @ C^T + D*x
// Block = one 64-row chunk x one 512-col half (grid = 512*2).
//   1. stage pre-scan Bx tile (64x256 f16 = 32KB) -> LDS lb, XOR-swizzled.
//   2. in-LDS scan: thread = state n, h = carry[chunk][n]; 64 serial f32
//      fmaf steps, f16 writeback (identical numerics to old scan_apply).
//   3. af fragments (wave's 16 rows x 256 k) from LDS -> registers. lb dead.
//   4. R4's slab loop REUSING lb as the 32KB C-slab: coalesced half8 fill
//      from L2-resident Ch, swizzled ds_read_b128 fragments, swapped-operand
//      MFMA -> lane owns 4 consecutive y cols -> float4 x/D loads, y stores.
// ---------------------------------------------------------------------------
__global__ __launch_bounds__(256, 4) void gemm_y_scan(
    const _Float16* __restrict__ Bxh, const _Float16* __restrict__ Ch,
    const float* __restrict__ x, const float* __restrict__ Dp,
    const float* __restrict__ Ap, const float* __restrict__ carry,
    float* __restrict__ y)
{
  __shared__ _Float16 lb[64 * 256];   // 32KB: Bx tile, then reused as C-slab

  const int tid  = threadIdx.x;
  const int lane = tid & 63;
  const int wave = tid >> 6;          // 0..3
  const int quad = lane >> 4;
  const int l16  = lane & 15;
  const int cg   = blockIdx.x & 1;    // column half: cols cg*512 .. +511
  const long mg  = blockIdx.x >> 1;   // chunk 0..511

  // 1. stage pre-scan Bx tile, flat coalesced half8 loads, XOR swizzle dest.
  //    64x256 f16 = 16384 elems = 8 iters x 256 thr x 8 halfs (r in 0..63).
  {
    const _Float16* src = Bxh + mg * 64 * 256;
    #pragma unroll
    for (int p = 0; p < 8; p++) {
      half8 v = *(const half8*)(src + p * 2048 + tid * 8);
      const int r   = p * 8 + (tid >> 5);          // tile row (time step)
      const int k8p = (tid & 31) ^ (r & 7);
      *(half8*)&lb[r * 256 + k8p * 8] = v;
    }
  }
  __syncthreads();

  // 2. in-LDS scan: thread owns state n = tid. Same math as old scan_apply.
  {
    const float al = expf(-expf(Ap[tid]));
    float h = carry[mg * 256 + tid];
    const int k8 = tid >> 3, e = tid & 7;
    #pragma unroll 8
    for (int t = 0; t < 64; t++) {
      const int idx = t * 256 + ((k8 ^ (t & 7)) * 8 + e);
      h = fmaf(al, h, (float)lb[idx]);
      lb[idx] = (_Float16)h;
    }
  }
  __syncthreads();

  // 3. af fragments from LDS: wave's 16 rows x 256 k (8 x ds_read_b128).
  const long row = mg * 64 + wave * 16 + l16;     // this lane's y row
  half8 af[8];
  {
    const int r = wave * 16 + l16;
    #pragma unroll
    for (int ks = 0; ks < 8; ks++) {
      const int k8p = (ks * 4 + quad) ^ (r & 7);
      af[ks] = *(const half8*)&lb[r * 256 + k8p * 8];
    }
  }

  // 4. slab loop, lb reused as C-slab (R4-verified pattern).
  const int nfill = tid >> 2, qfill = tid & 3;    // C-slab fill role
  const float* px = x + row * 1024;
  float*       py = y + row * 1024;

  for (int it = 0; it < 8; it++) {
    const int n0 = cg * 512 + it * 64;

    __syncthreads();   // prev slab readers done (it=0: af/scan reads done)
    // fill C-slab: thread -> n = tid>>2 (0..63), q = tid&3 (8 x 16B)
    {
      const _Float16* src = Ch + (size_t)(n0 + nfill) * 256 + qfill * 64;
      #pragma unroll
      for (int j = 0; j < 8; j++) {
        half8 v = *(const half8*)(src + j * 8);
        const int k8p = (qfill * 8 + j) ^ (nfill & 7);
        *(half8*)&lb[nfill * 256 + k8p * 8] = v;
      }
    }

    // independent of LDS: this lane's x tile + D for this slab (issue early)
    float4 xv[4], dv[4];
    #pragma unroll
    for (int nt = 0; nt < 4; nt++) {
      xv[nt] = *(const float4*)(px + n0 + nt * 16 + quad * 4);
      dv[nt] = *(const float4*)(Dp + n0 + nt * 16 + quad * 4);
    }

    __syncthreads();                  // slab visible

    f32x4 acc[4];
    #pragma unroll
    for (int nt = 0; nt < 4; nt++) acc[nt] = (f32x4){0.f, 0.f, 0.f, 0.f};

    #pragma unroll
    for (int ks = 0; ks < 8; ks++) {
      #pragma unroll
      for (int nt = 0; nt < 4; nt++) {
        const int nl  = nt * 16 + l16;
        const int k8p = (ks * 4 + quad) ^ (nl & 7);
        half8 cf = *(const half8*)&lb[nl * 256 + k8p * 8];
        acc[nt] = __builtin_amdgcn_mfma_f32_16x16x32_f16(cf, af[ks], acc[nt], 0, 0, 0);
      }
    }

    // epilogue: y = acc + D*x, 4 consecutive cols per lane (float4 stores)
    #pragma unroll
    for (int nt = 0; nt < 4; nt++) {
      float4 o;
      o.x = acc[nt][0] + dv[nt].x * xv[nt].x;
      o.y = acc[nt][1] + dv[nt].y * xv[nt].y;
      o.z = acc[nt][2] + dv[nt].z * xv[nt].z;
      o.w = acc[nt][3] + dv[nt].w * xv[nt].w;
      *(float4*)(py + n0 + nt * 16 + quad * 4) = o;
    }
  }
}

// ---------------------------------------------------------------------------
extern "C" void kernel_launch(void* const* d_in, const int* in_sizes, int n_in,
                              void* d_out, int out_size, void* d_ws, size_t ws_size,
                              hipStream_t stream) {
  const float* x  = (const float*)d_in[0];
  const float* Ap = (const float*)d_in[1];
  const float* Bp = (const float*)d_in[2];
  const float* Cp = (const float*)d_in[3];
  const float* Dp = (const float*)d_in[4];
  float* y = (float*)d_out;

  // ws: Bxh 16.8MB | Bh 512KB | Ch 512KB | E 512KB | carry 512KB
  _Float16* Bxh = (_Float16*)d_ws;
  _Float16* Bh  = Bxh + (size_t)32768 * 256;
  _Float16* Ch  = Bh + (size_t)256 * 1024;
  float* E      = (float*)(Ch + (size_t)1024 * 256);
  float* carry  = E + (size_t)512 * 256;

  cvt_bc     <<<256,  256, 0, stream>>>(Bp, Cp, Bh, Ch);
  gemm_bx    <<<512,  256, 0, stream>>>(x, Bh, Ap, Bxh, E);
  scan_prefix<<<8,    256, 0, stream>>>(E, Ap, carry);
  gemm_y_scan<<<1024, 256, 0, stream>>>(Bxh, Ch, x, Dp, Ap, carry, y);
}